// Round 1
// baseline (435.758 us; speedup 1.0000x reference)
//
#include <hip/hip_runtime.h>
#include <hip/hip_bf16.h>

typedef __bf16 bf16;
typedef __attribute__((ext_vector_type(8))) __bf16 bf16x8;
typedef __attribute__((ext_vector_type(4))) __bf16 bf16x4;
typedef __attribute__((ext_vector_type(2))) __bf16 bf16x2;
typedef __attribute__((ext_vector_type(4))) float f32x4;

// Problem constants
#define BB 2
#define SS 2048
#define HH 2048
#define NH 16
#define HD 128

// ---------------------------------------------------------------------------
// fp32 -> bf16 cast, 4 elements/thread
// ---------------------------------------------------------------------------
__global__ __launch_bounds__(256) void cast_f32_bf16(const float* __restrict__ in,
                                                     bf16* __restrict__ out, int n4) {
    int i = blockIdx.x * 256 + threadIdx.x;
    if (i < n4) {
        f32x4 v = *reinterpret_cast<const f32x4*>(in + (size_t)i * 4);
        bf16x4 o;
        o[0] = (bf16)v[0]; o[1] = (bf16)v[1]; o[2] = (bf16)v[2]; o[3] = (bf16)v[3];
        *reinterpret_cast<bf16x4*>(out + (size_t)i * 4) = o;
    }
}

// ---------------------------------------------------------------------------
// GEMM: C[m,n] = sum_k A[m,k] * B[n,k]   (A: MxK bf16 row-major, B: NxK bf16)
// EPI=0: store bf16 into per-head layout [B][NH][S][HD] (m=b*S+s, n=h*HD+d)
// EPI=1: store fp32 row-major [M][N]
// block = 256 threads (4 waves), tile 128x128, BK=64
// ---------------------------------------------------------------------------
template <int EPI>
__global__ __launch_bounds__(256) void gemm_bt(const bf16* __restrict__ A,
                                               const bf16* __restrict__ B,
                                               float* __restrict__ Cf,
                                               bf16* __restrict__ Cb,
                                               int M, int N, int K) {
    constexpr int BK = 64, PAD = 8;
    __shared__ bf16 As[128][BK + PAD];
    __shared__ bf16 Bs[128][BK + PAD];
    const int tid = threadIdx.x;
    const int lane = tid & 63, wave = tid >> 6;
    const int l15 = lane & 15, lhi = lane >> 4;
    const int m0 = blockIdx.y * 128, n0 = blockIdx.x * 128;
    const int wm = (wave >> 1) * 64, wn = (wave & 1) * 64;

    f32x4 acc[4][4] = {};

    for (int k0 = 0; k0 < K; k0 += BK) {
#pragma unroll
        for (int i = 0; i < 4; ++i) {
            int id = tid + i * 256;          // 0..1023
            int row = id >> 3, cg = (id & 7) * 8;
            *reinterpret_cast<bf16x8*>(&As[row][cg]) =
                *reinterpret_cast<const bf16x8*>(&A[(size_t)(m0 + row) * K + k0 + cg]);
            *reinterpret_cast<bf16x8*>(&Bs[row][cg]) =
                *reinterpret_cast<const bf16x8*>(&B[(size_t)(n0 + row) * K + k0 + cg]);
        }
        __syncthreads();
#pragma unroll
        for (int ks = 0; ks < 2; ++ks) {
            bf16x8 af[4], bfr[4];
#pragma unroll
            for (int i = 0; i < 4; ++i)
                af[i] = *reinterpret_cast<const bf16x8*>(&As[wm + i * 16 + l15][ks * 32 + 8 * lhi]);
#pragma unroll
            for (int j = 0; j < 4; ++j)
                bfr[j] = *reinterpret_cast<const bf16x8*>(&Bs[wn + j * 16 + l15][ks * 32 + 8 * lhi]);
#pragma unroll
            for (int i = 0; i < 4; ++i)
#pragma unroll
                for (int j = 0; j < 4; ++j)
                    acc[i][j] = __builtin_amdgcn_mfma_f32_16x16x32_bf16(af[i], bfr[j], acc[i][j], 0, 0, 0);
        }
        __syncthreads();
    }

#pragma unroll
    for (int i = 0; i < 4; ++i)
#pragma unroll
        for (int j = 0; j < 4; ++j)
#pragma unroll
            for (int r = 0; r < 4; ++r) {
                int gm = m0 + wm + i * 16 + lhi * 4 + r;
                int gn = n0 + wn + j * 16 + l15;
                float v = acc[i][j][r];
                if (EPI == 0) {
                    int b = gm >> 11, s = gm & (SS - 1);
                    int h = gn >> 7, d = gn & (HD - 1);
                    Cb[(((size_t)(b * NH + h)) * SS + s) * HD + d] = (bf16)v;
                } else {
                    Cf[(size_t)gm * N + gn] = v;
                }
            }
}

// ---------------------------------------------------------------------------
// RoPE (rotate_half convention), in-place on Q and K, per-head layout
// one thread per (head, s, d<64) pair; handles both halves, both Q and K
// ---------------------------------------------------------------------------
__global__ __launch_bounds__(256) void rope_kernel(bf16* __restrict__ Qh, bf16* __restrict__ Kh,
                                                   const float* __restrict__ cosT,
                                                   const float* __restrict__ sinT) {
    size_t idx = (size_t)blockIdx.x * 256 + threadIdx.x;  // < 32*2048*64
    int d = idx & 63;
    int s = (idx >> 6) & (SS - 1);
    int head = idx >> 17;
    size_t base = ((size_t)head * SS + s) * HD;
    float c = cosT[s * HD + d];
    float sn = sinT[s * HD + d];
    float q0 = (float)Qh[base + d], q1 = (float)Qh[base + d + 64];
    float k0 = (float)Kh[base + d], k1 = (float)Kh[base + d + 64];
    Qh[base + d]      = (bf16)(q0 * c - q1 * sn);
    Qh[base + d + 64] = (bf16)(q1 * c + q0 * sn);
    Kh[base + d]      = (bf16)(k0 * c - k1 * sn);
    Kh[base + d + 64] = (bf16)(k1 * c + k0 * sn);
}

// ---------------------------------------------------------------------------
// Causal flash attention. grid = (S/128, B*NH), block = 256 (4 waves).
// Each wave owns 32 q-rows. KV tiled by 64. Output written as [B*S][H] bf16.
// ---------------------------------------------------------------------------
__global__ __launch_bounds__(256) void attn_kernel(const bf16* __restrict__ Q,
                                                   const bf16* __restrict__ K,
                                                   const bf16* __restrict__ V,
                                                   bf16* __restrict__ Ob) {
    constexpr int QB = 128, KB = 64, PAD = 8;
    __shared__ bf16 Ks[KB][HD + PAD];
    __shared__ bf16 Vt[HD][KB + PAD];
    __shared__ bf16 Ps[4][32][KB + PAD];

    const int tid = threadIdx.x, lane = tid & 63, wave = tid >> 6;
    const int l15 = lane & 15, lhi = lane >> 4;
    const int head = blockIdx.y;            // b*NH + h
    const int b = head >> 4, h = head & (NH - 1);
    const int q0 = blockIdx.x * QB;
    const size_t hbase = (size_t)head * SS * HD;
    const int qw = q0 + wave * 32;
    const float scaling = 0.08838834764831845f;  // 1/sqrt(128)

    // Q fragments (2 m-frags x 4 k-steps over HD=128)
    bf16x8 qf[2][4];
#pragma unroll
    for (int me = 0; me < 2; ++me)
#pragma unroll
        for (int ks = 0; ks < 4; ++ks)
            qf[me][ks] = *reinterpret_cast<const bf16x8*>(
                &Q[hbase + (size_t)(qw + me * 16 + l15) * HD + ks * 32 + 8 * lhi]);

    f32x4 oacc[2][8] = {};
    float M2[2][4], L2[2][4];
#pragma unroll
    for (int me = 0; me < 2; ++me)
#pragma unroll
        for (int r = 0; r < 4; ++r) { M2[me][r] = -INFINITY; L2[me][r] = 0.f; }

    for (int kv0 = 0; kv0 < q0 + QB; kv0 += KB) {
        // stage K tile (row-major, k-contiguous = perfect B operand)
#pragma unroll
        for (int i = 0; i < 4; ++i) {
            int id = tid + i * 256;          // 0..1023 (64 rows x 16 groups)
            int row = id >> 4, cg = (id & 15) * 8;
            *reinterpret_cast<bf16x8*>(&Ks[row][cg]) =
                *reinterpret_cast<const bf16x8*>(&K[hbase + (size_t)(kv0 + row) * HD + cg]);
        }
        // stage V transposed: Vt[d][kv]
#pragma unroll
        for (int i = 0; i < 16; ++i) {
            int p = tid + i * 256;           // 0..4095 pairs
            int d = p & 127, vr2 = (p >> 7) * 2;
            bf16 v0 = V[hbase + (size_t)(kv0 + vr2) * HD + d];
            bf16 v1 = V[hbase + (size_t)(kv0 + vr2 + 1) * HD + d];
            bf16x2 pk = {v0, v1};
            *reinterpret_cast<bf16x2*>(&Vt[d][vr2]) = pk;
        }
        __syncthreads();

        // S = Q K^T
        f32x4 sf[2][4] = {};
#pragma unroll
        for (int ks = 0; ks < 4; ++ks) {
            bf16x8 kf[4];
#pragma unroll
            for (int ne = 0; ne < 4; ++ne)
                kf[ne] = *reinterpret_cast<const bf16x8*>(&Ks[ne * 16 + l15][ks * 32 + 8 * lhi]);
#pragma unroll
            for (int me = 0; me < 2; ++me)
#pragma unroll
                for (int ne = 0; ne < 4; ++ne)
                    sf[me][ne] = __builtin_amdgcn_mfma_f32_16x16x32_bf16(qf[me][ks], kf[ne], sf[me][ne], 0, 0, 0);
        }

        // online softmax per wave-row
#pragma unroll
        for (int me = 0; me < 2; ++me) {
            float rmax[4];
#pragma unroll
            for (int r = 0; r < 4; ++r) rmax[r] = -INFINITY;
#pragma unroll
            for (int ne = 0; ne < 4; ++ne)
#pragma unroll
                for (int r = 0; r < 4; ++r) {
                    int gq = qw + me * 16 + lhi * 4 + r;
                    int gk = kv0 + ne * 16 + l15;
                    float sv = sf[me][ne][r] * scaling;
                    sv = (gk <= gq) ? sv : -INFINITY;
                    sf[me][ne][r] = sv;
                    rmax[r] = fmaxf(rmax[r], sv);
                }
#pragma unroll
            for (int m = 1; m < 16; m <<= 1)
#pragma unroll
                for (int r = 0; r < 4; ++r)
                    rmax[r] = fmaxf(rmax[r], __shfl_xor(rmax[r], m));

            float nM[4], sc[4], rsum[4];
#pragma unroll
            for (int r = 0; r < 4; ++r) {
                nM[r] = fmaxf(M2[me][r], rmax[r]);
                sc[r] = __expf(M2[me][r] - nM[r]);
                M2[me][r] = nM[r];
                rsum[r] = 0.f;
            }
#pragma unroll
            for (int ne = 0; ne < 4; ++ne)
#pragma unroll
                for (int r = 0; r < 4; ++r) {
                    float p = __expf(sf[me][ne][r] - nM[r]);
                    rsum[r] += p;
                    Ps[wave][me * 16 + lhi * 4 + r][ne * 16 + l15] = (bf16)p;
                }
#pragma unroll
            for (int m = 1; m < 16; m <<= 1)
#pragma unroll
                for (int r = 0; r < 4; ++r)
                    rsum[r] += __shfl_xor(rsum[r], m);
#pragma unroll
            for (int r = 0; r < 4; ++r)
                L2[me][r] = L2[me][r] * sc[r] + rsum[r];
#pragma unroll
            for (int nf = 0; nf < 8; ++nf)
#pragma unroll
                for (int r = 0; r < 4; ++r)
                    oacc[me][nf][r] *= sc[r];
        }

        // O += P @ V
#pragma unroll
        for (int ks = 0; ks < 2; ++ks) {
            bf16x8 pa[2];
#pragma unroll
            for (int me = 0; me < 2; ++me)
                pa[me] = *reinterpret_cast<const bf16x8*>(&Ps[wave][me * 16 + l15][ks * 32 + 8 * lhi]);
#pragma unroll
            for (int nf = 0; nf < 8; ++nf) {
                bf16x8 vb = *reinterpret_cast<const bf16x8*>(&Vt[nf * 16 + l15][ks * 32 + 8 * lhi]);
#pragma unroll
                for (int me = 0; me < 2; ++me)
                    oacc[me][nf] = __builtin_amdgcn_mfma_f32_16x16x32_bf16(pa[me], vb, oacc[me][nf], 0, 0, 0);
            }
        }
        __syncthreads();
    }

    // epilogue: divide by L, write [B*S][H] bf16
#pragma unroll
    for (int me = 0; me < 2; ++me)
#pragma unroll
        for (int nf = 0; nf < 8; ++nf)
#pragma unroll
            for (int r = 0; r < 4; ++r) {
                int s = qw + me * 16 + lhi * 4 + r;
                int d = nf * 16 + l15;
                float v = oacc[me][nf][r] / L2[me][r];
                Ob[((size_t)(b * SS + s)) * HH + h * HD + d] = (bf16)v;
            }
}

// ---------------------------------------------------------------------------
extern "C" void kernel_launch(void* const* d_in, const int* in_sizes, int n_in,
                              void* d_out, int out_size, void* d_ws, size_t ws_size,
                              hipStream_t stream) {
    const float* hs   = (const float*)d_in[0];
    const float* cosT = (const float*)d_in[2];
    const float* sinT = (const float*)d_in[3];
    const float* Wq   = (const float*)d_in[4];
    const float* Wk   = (const float*)d_in[5];
    const float* Wv   = (const float*)d_in[6];
    const float* Wo   = (const float*)d_in[7];
    float* out = (float*)d_out;

    char* w = (char*)d_ws;
    auto alloc = [&](size_t bytes) {
        char* p = w;
        w += (bytes + 255) & ~(size_t)255;
        return p;
    };
    const size_t XB_BYTES = (size_t)BB * SS * HH * 2;       // 16.78 MB
    const size_t W_BYTES  = (size_t)HH * HH * 2;            // 8.39 MB
    bf16* Xb  = (bf16*)alloc(XB_BYTES);
    bf16* Wqb = (bf16*)alloc(W_BYTES);
    bf16* Wkb = (bf16*)alloc(W_BYTES);
    bf16* Wvb = (bf16*)alloc(W_BYTES);
    bf16* Wob = (bf16*)alloc(W_BYTES);
    bf16* Qh  = (bf16*)alloc(XB_BYTES);
    bf16* Kh  = (bf16*)alloc(XB_BYTES);
    bf16* Vh  = (bf16*)alloc(XB_BYTES);
    bf16* Ob  = (bf16*)alloc(XB_BYTES);

    const int M = BB * SS;  // 4096

    // casts
    cast_f32_bf16<<<(M * HH / 4 + 255) / 256, 256, 0, stream>>>(hs, Xb, M * HH / 4);
    cast_f32_bf16<<<(HH * HH / 4 + 255) / 256, 256, 0, stream>>>(Wq, Wqb, HH * HH / 4);
    cast_f32_bf16<<<(HH * HH / 4 + 255) / 256, 256, 0, stream>>>(Wk, Wkb, HH * HH / 4);
    cast_f32_bf16<<<(HH * HH / 4 + 255) / 256, 256, 0, stream>>>(Wv, Wvb, HH * HH / 4);
    cast_f32_bf16<<<(HH * HH / 4 + 255) / 256, 256, 0, stream>>>(Wo, Wob, HH * HH / 4);

    // Q/K/V projections (write per-head layout)
    dim3 ggrid(HH / 128, M / 128);
    gemm_bt<0><<<ggrid, 256, 0, stream>>>(Xb, Wqb, nullptr, Qh, M, HH, HH);
    gemm_bt<0><<<ggrid, 256, 0, stream>>>(Xb, Wkb, nullptr, Kh, M, HH, HH);
    gemm_bt<0><<<ggrid, 256, 0, stream>>>(Xb, Wvb, nullptr, Vh, M, HH, HH);

    // RoPE on Q,K in place
    rope_kernel<<<(BB * NH * SS * 64) / 256, 256, 0, stream>>>(Qh, Kh, cosT, sinT);

    // attention
    dim3 agrid(SS / 128, BB * NH);
    attn_kernel<<<agrid, 256, 0, stream>>>(Qh, Kh, Vh, Ob);

    // output projection (fp32 row-major)
    gemm_bt<1><<<ggrid, 256, 0, stream>>>(Ob, Wob, out, nullptr, M, HH, HH);
}

// Round 2
// 327.447 us; speedup vs baseline: 1.3308x; 1.3308x over previous
//
#include <hip/hip_runtime.h>
#include <hip/hip_bf16.h>

typedef __bf16 bf16;
typedef __attribute__((ext_vector_type(8))) __bf16 bf16x8;
typedef __attribute__((ext_vector_type(4))) __bf16 bf16x4;
typedef __attribute__((ext_vector_type(4))) float f32x4;

// Problem constants
#define BB 2
#define SS 2048
#define HH 2048
#define NH 16
#define HD 128

// ---------------------------------------------------------------------------
// fp32 -> bf16 cast, 4 elements/thread
// ---------------------------------------------------------------------------
__global__ __launch_bounds__(256) void cast_f32_bf16(const float* __restrict__ in,
                                                     bf16* __restrict__ out, int n4) {
    int i = blockIdx.x * 256 + threadIdx.x;
    if (i < n4) {
        f32x4 v = *reinterpret_cast<const f32x4*>(in + (size_t)i * 4);
        bf16x4 o;
        o[0] = (bf16)v[0]; o[1] = (bf16)v[1]; o[2] = (bf16)v[2]; o[3] = (bf16)v[3];
        *reinterpret_cast<bf16x4*>(out + (size_t)i * 4) = o;
    }
}

// ---------------------------------------------------------------------------
// GEMM: C[m,n] = sum_k A[m,k] * B[n,k]   (A: MxK bf16 row-major, B: NxK bf16)
// EPI=0: store bf16 into per-head layout [B][NH][S][HD] (m=b*S+s, n=h*HD+d)
// EPI=1: store fp32 row-major [M][N]
// ---------------------------------------------------------------------------
template <int EPI>
__global__ __launch_bounds__(256) void gemm_bt(const bf16* __restrict__ A,
                                               const bf16* __restrict__ B,
                                               float* __restrict__ Cf,
                                               bf16* __restrict__ Cb,
                                               int M, int N, int K) {
    constexpr int BK = 64, PAD = 8;
    __shared__ bf16 As[128][BK + PAD];
    __shared__ bf16 Bs[128][BK + PAD];
    const int tid = threadIdx.x;
    const int lane = tid & 63, wave = tid >> 6;
    const int l15 = lane & 15, lhi = lane >> 4;
    const int m0 = blockIdx.y * 128, n0 = blockIdx.x * 128;
    const int wm = (wave >> 1) * 64, wn = (wave & 1) * 64;

    f32x4 acc[4][4] = {};

    for (int k0 = 0; k0 < K; k0 += BK) {
#pragma unroll
        for (int i = 0; i < 4; ++i) {
            int id = tid + i * 256;
            int row = id >> 3, cg = (id & 7) * 8;
            *reinterpret_cast<bf16x8*>(&As[row][cg]) =
                *reinterpret_cast<const bf16x8*>(&A[(size_t)(m0 + row) * K + k0 + cg]);
            *reinterpret_cast<bf16x8*>(&Bs[row][cg]) =
                *reinterpret_cast<const bf16x8*>(&B[(size_t)(n0 + row) * K + k0 + cg]);
        }
        __syncthreads();
#pragma unroll
        for (int ks = 0; ks < 2; ++ks) {
            bf16x8 af[4], bfr[4];
#pragma unroll
            for (int i = 0; i < 4; ++i)
                af[i] = *reinterpret_cast<const bf16x8*>(&As[wm + i * 16 + l15][ks * 32 + 8 * lhi]);
#pragma unroll
            for (int j = 0; j < 4; ++j)
                bfr[j] = *reinterpret_cast<const bf16x8*>(&Bs[wn + j * 16 + l15][ks * 32 + 8 * lhi]);
#pragma unroll
            for (int i = 0; i < 4; ++i)
#pragma unroll
                for (int j = 0; j < 4; ++j)
                    acc[i][j] = __builtin_amdgcn_mfma_f32_16x16x32_bf16(af[i], bfr[j], acc[i][j], 0, 0, 0);
        }
        __syncthreads();
    }

#pragma unroll
    for (int i = 0; i < 4; ++i)
#pragma unroll
        for (int j = 0; j < 4; ++j)
#pragma unroll
            for (int r = 0; r < 4; ++r) {
                int gm = m0 + wm + i * 16 + lhi * 4 + r;
                int gn = n0 + wn + j * 16 + l15;
                float v = acc[i][j][r];
                if (EPI == 0) {
                    int b = gm >> 11, s = gm & (SS - 1);
                    int h = gn >> 7, d = gn & (HD - 1);
                    Cb[(((size_t)(b * NH + h)) * SS + s) * HD + d] = (bf16)v;
                } else {
                    Cf[(size_t)gm * N + gn] = v;
                }
            }
}

// ---------------------------------------------------------------------------
// Transpose V per head: Vh[head][s][d] -> Vt[head][d][s]
// 64x64 tiles, XOR-swizzled LDS (conflict-free both sides), vectorized I/O.
// grid (SS/64, HD/64, B*NH), block 256
// ---------------------------------------------------------------------------
__global__ __launch_bounds__(256) void transpose_v(const bf16* __restrict__ Vh,
                                                   bf16* __restrict__ Vt) {
    __shared__ bf16 T[64 * 64];
    const int tid = threadIdx.x;
    const int s0 = blockIdx.x * 64, d0 = blockIdx.y * 64, head = blockIdx.z;
    const bf16* src = Vh + ((size_t)head * SS) * HD;
    bf16* dst = Vt + ((size_t)head * HD) * SS;

    // element (r=s-local, c=d-local) lives at byte r*128 + ((c>>3)^((r^(r>>3))&7))*16 + (c&7)*2
#pragma unroll
    for (int i = 0; i < 2; ++i) {
        int id = tid + i * 256;              // 0..511
        int r = id >> 3, c16 = id & 7;
        bf16x8 v = *reinterpret_cast<const bf16x8*>(&src[(size_t)(s0 + r) * HD + d0 + c16 * 8]);
        int sw = c16 ^ ((r ^ (r >> 3)) & 7);
        *reinterpret_cast<bf16x8*>((char*)T + r * 128 + sw * 16) = v;
    }
    __syncthreads();
#pragma unroll
    for (int i = 0; i < 2; ++i) {
        int id = tid + i * 256;
        int dr = id >> 3, sc8 = (id & 7) * 8;
        bf16x8 o;
#pragma unroll
        for (int j = 0; j < 8; ++j) {
            int r = sc8 + j;
            int sw = (dr >> 3) ^ ((r ^ (r >> 3)) & 7);
            o[j] = *reinterpret_cast<const bf16*>((char*)T + r * 128 + sw * 16 + (dr & 7) * 2);
        }
        *reinterpret_cast<bf16x8*>(&dst[(size_t)(d0 + dr) * SS + s0 + sc8]) = o;
    }
}

// ---------------------------------------------------------------------------
// RoPE (rotate_half), vectorized: 8 d-elements (both halves) per thread.
// ---------------------------------------------------------------------------
__global__ __launch_bounds__(256) void rope_kernel(bf16* __restrict__ Qh, bf16* __restrict__ Kh,
                                                   const float* __restrict__ cosT,
                                                   const float* __restrict__ sinT) {
    int idx = blockIdx.x * 256 + threadIdx.x;   // < 32*2048*8
    int g = idx & 7;
    int s = (idx >> 3) & (SS - 1);
    int head = idx >> 14;
    int d0 = g * 8;
    size_t base = ((size_t)head * SS + s) * HD;
    f32x4 ca = *reinterpret_cast<const f32x4*>(&cosT[s * HD + d0]);
    f32x4 cb = *reinterpret_cast<const f32x4*>(&cosT[s * HD + d0 + 4]);
    f32x4 sa = *reinterpret_cast<const f32x4*>(&sinT[s * HD + d0]);
    f32x4 sb = *reinterpret_cast<const f32x4*>(&sinT[s * HD + d0 + 4]);
    bf16x8 ql = *reinterpret_cast<const bf16x8*>(&Qh[base + d0]);
    bf16x8 qh = *reinterpret_cast<const bf16x8*>(&Qh[base + 64 + d0]);
    bf16x8 kl = *reinterpret_cast<const bf16x8*>(&Kh[base + d0]);
    bf16x8 kh = *reinterpret_cast<const bf16x8*>(&Kh[base + 64 + d0]);
    bf16x8 qlo, qhi, klo, khi;
#pragma unroll
    for (int j = 0; j < 8; ++j) {
        float c = (j < 4) ? ca[j] : cb[j - 4];
        float sn = (j < 4) ? sa[j] : sb[j - 4];
        float q0 = (float)ql[j], q1 = (float)qh[j];
        float k0 = (float)kl[j], k1 = (float)kh[j];
        qlo[j] = (bf16)(q0 * c - q1 * sn);
        qhi[j] = (bf16)(q1 * c + q0 * sn);
        klo[j] = (bf16)(k0 * c - k1 * sn);
        khi[j] = (bf16)(k1 * c + k0 * sn);
    }
    *reinterpret_cast<bf16x8*>(&Qh[base + d0]) = qlo;
    *reinterpret_cast<bf16x8*>(&Qh[base + 64 + d0]) = qhi;
    *reinterpret_cast<bf16x8*>(&Kh[base + d0]) = klo;
    *reinterpret_cast<bf16x8*>(&Kh[base + 64 + d0]) = khi;
}

// ---------------------------------------------------------------------------
// Causal flash attention, load-balanced.
// QB=64, KB=64. grid = 512 blocks (1D), block = 256 (4 waves x 16 q-rows).
// Block processes q-tile pair (t, 31-t): uniform 33 KV-tiles per block.
// V comes pre-transposed: Vt[head][d][s].
// ---------------------------------------------------------------------------
__global__ __launch_bounds__(256) void attn_kernel(const bf16* __restrict__ Q,
                                                   const bf16* __restrict__ K,
                                                   const bf16* __restrict__ Vt,
                                                   bf16* __restrict__ Ob) {
    constexpr int NT = SS / 64;  // 32
    __shared__ bf16 Ks[64][136];      // 17408 B  (stride 272B: 2-way reads)
    __shared__ bf16 Vs[128][72];      // 18432 B  (stride 144B: 2-way reads)
    __shared__ bf16 Ps[4][16][72];    //  9216 B

    const int tid = threadIdx.x, lane = tid & 63, wave = tid >> 6;
    const int l15 = lane & 15, lhi = lane >> 4;
    const int bid = blockIdx.x;
    const int orig = (bid & 7) * 64 + (bid >> 3);   // XCD swizzle (512 % 8 == 0)
    const int head = orig >> 4;
    const int pi = orig & 15;
    const int b = head >> 4, h = head & (NH - 1);
    const size_t hb = (size_t)head * SS * HD;
    const bf16* Vth = Vt + (size_t)head * HD * SS;
    const float scaling = 0.08838834764831845f;  // 1/sqrt(128)

#pragma unroll 1
    for (int part = 0; part < 2; ++part) {
        const int t = part ? (NT - 1 - pi) : pi;
        const int q0 = t * 64;
        const int qw = q0 + wave * 16;

        bf16x8 qf[4];
#pragma unroll
        for (int ks = 0; ks < 4; ++ks)
            qf[ks] = *reinterpret_cast<const bf16x8*>(
                &Q[hb + (size_t)(qw + l15) * HD + ks * 32 + 8 * lhi]);

        f32x4 oacc[8] = {};
        float Mr[4], Lr[4];
#pragma unroll
        for (int r = 0; r < 4; ++r) { Mr[r] = -INFINITY; Lr[r] = 0.f; }

        const int nkv = (q0 >> 6) + 1;
        for (int it = 0; it < nkv; ++it) {
            const int kv0 = it * 64;
            // ---- stage K tile (row-major) and Vt tile (d-major) ----
#pragma unroll
            for (int i = 0; i < 4; ++i) {
                int id = tid + i * 256;          // 0..1023
                int row = id >> 4, cg = (id & 15) * 8;
                *reinterpret_cast<bf16x8*>(&Ks[row][cg]) =
                    *reinterpret_cast<const bf16x8*>(&K[hb + (size_t)(kv0 + row) * HD + cg]);
            }
#pragma unroll
            for (int i = 0; i < 4; ++i) {
                int id = tid + i * 256;          // 0..1023
                int row = id >> 3, cg = (id & 7) * 8;
                *reinterpret_cast<bf16x8*>(&Vs[row][cg]) =
                    *reinterpret_cast<const bf16x8*>(&Vth[(size_t)row * SS + kv0 + cg]);
            }
            __syncthreads();

            // ---- S = Q K^T ----
            f32x4 sf[4] = {};
#pragma unroll
            for (int ks = 0; ks < 4; ++ks) {
#pragma unroll
                for (int ne = 0; ne < 4; ++ne) {
                    bf16x8 kf = *reinterpret_cast<const bf16x8*>(&Ks[ne * 16 + l15][ks * 32 + 8 * lhi]);
                    sf[ne] = __builtin_amdgcn_mfma_f32_16x16x32_bf16(qf[ks], kf, sf[ne], 0, 0, 0);
                }
            }

            // ---- online softmax (rows = lhi*4+r, cols = ne*16+l15) ----
            const bool diag = (kv0 == q0);
            float rmax[4];
#pragma unroll
            for (int r = 0; r < 4; ++r) rmax[r] = -INFINITY;
#pragma unroll
            for (int ne = 0; ne < 4; ++ne)
#pragma unroll
                for (int r = 0; r < 4; ++r) {
                    float sv = sf[ne][r] * scaling;
                    if (diag) {
                        int gq = qw + lhi * 4 + r, gk = kv0 + ne * 16 + l15;
                        sv = (gk <= gq) ? sv : -INFINITY;
                    }
                    sf[ne][r] = sv;
                    rmax[r] = fmaxf(rmax[r], sv);
                }
#pragma unroll
            for (int m = 1; m < 16; m <<= 1)
#pragma unroll
                for (int r = 0; r < 4; ++r)
                    rmax[r] = fmaxf(rmax[r], __shfl_xor(rmax[r], m));

            float sc[4], rsum[4];
#pragma unroll
            for (int r = 0; r < 4; ++r) {
                float nM = fmaxf(Mr[r], rmax[r]);
                sc[r] = __expf(Mr[r] - nM);
                Mr[r] = nM;
                rsum[r] = 0.f;
            }
#pragma unroll
            for (int ne = 0; ne < 4; ++ne)
#pragma unroll
                for (int r = 0; r < 4; ++r) {
                    float p = __expf(sf[ne][r] - Mr[r]);
                    rsum[r] += p;
                    Ps[wave][lhi * 4 + r][ne * 16 + l15] = (bf16)p;
                }
#pragma unroll
            for (int m = 1; m < 16; m <<= 1)
#pragma unroll
                for (int r = 0; r < 4; ++r)
                    rsum[r] += __shfl_xor(rsum[r], m);
#pragma unroll
            for (int r = 0; r < 4; ++r)
                Lr[r] = Lr[r] * sc[r] + rsum[r];
#pragma unroll
            for (int nf = 0; nf < 8; ++nf)
#pragma unroll
                for (int r = 0; r < 4; ++r)
                    oacc[nf][r] *= sc[r];

            // ---- O += P @ V  (B operand straight from d-major Vs) ----
#pragma unroll
            for (int ks = 0; ks < 2; ++ks) {
                bf16x8 pa = *reinterpret_cast<const bf16x8*>(&Ps[wave][l15][ks * 32 + 8 * lhi]);
#pragma unroll
                for (int nf = 0; nf < 8; ++nf) {
                    bf16x8 vb = *reinterpret_cast<const bf16x8*>(&Vs[nf * 16 + l15][ks * 32 + 8 * lhi]);
                    oacc[nf] = __builtin_amdgcn_mfma_f32_16x16x32_bf16(pa, vb, oacc[nf], 0, 0, 0);
                }
            }
            __syncthreads();
        }

        // ---- epilogue: write [B*S][H] bf16 ----
        float inv[4];
#pragma unroll
        for (int r = 0; r < 4; ++r) inv[r] = 1.f / Lr[r];
#pragma unroll
        for (int nf = 0; nf < 8; ++nf)
#pragma unroll
            for (int r = 0; r < 4; ++r) {
                int s = qw + lhi * 4 + r;
                int d = nf * 16 + l15;
                Ob[((size_t)(b * SS + s)) * HH + h * HD + d] = (bf16)(oacc[nf][r] * inv[r]);
            }
    }
}

// ---------------------------------------------------------------------------
extern "C" void kernel_launch(void* const* d_in, const int* in_sizes, int n_in,
                              void* d_out, int out_size, void* d_ws, size_t ws_size,
                              hipStream_t stream) {
    const float* hs   = (const float*)d_in[0];
    const float* cosT = (const float*)d_in[2];
    const float* sinT = (const float*)d_in[3];
    const float* Wq   = (const float*)d_in[4];
    const float* Wk   = (const float*)d_in[5];
    const float* Wv   = (const float*)d_in[6];
    const float* Wo   = (const float*)d_in[7];
    float* out = (float*)d_out;

    char* w = (char*)d_ws;
    auto alloc = [&](size_t bytes) {
        char* p = w;
        w += (bytes + 255) & ~(size_t)255;
        return p;
    };
    const size_t XB_BYTES = (size_t)BB * SS * HH * 2;
    const size_t W_BYTES  = (size_t)HH * HH * 2;
    bf16* Xb  = (bf16*)alloc(XB_BYTES);
    bf16* Wqb = (bf16*)alloc(W_BYTES);
    bf16* Wkb = (bf16*)alloc(W_BYTES);
    bf16* Wvb = (bf16*)alloc(W_BYTES);
    bf16* Wob = (bf16*)alloc(W_BYTES);
    bf16* Qh  = (bf16*)alloc(XB_BYTES);
    bf16* Kh  = (bf16*)alloc(XB_BYTES);
    bf16* Vh  = (bf16*)alloc(XB_BYTES);
    bf16* Vtg = (bf16*)alloc(XB_BYTES);
    bf16* Ob  = (bf16*)alloc(XB_BYTES);

    const int M = BB * SS;  // 4096

    cast_f32_bf16<<<(M * HH / 4 + 255) / 256, 256, 0, stream>>>(hs, Xb, M * HH / 4);
    cast_f32_bf16<<<(HH * HH / 4 + 255) / 256, 256, 0, stream>>>(Wq, Wqb, HH * HH / 4);
    cast_f32_bf16<<<(HH * HH / 4 + 255) / 256, 256, 0, stream>>>(Wk, Wkb, HH * HH / 4);
    cast_f32_bf16<<<(HH * HH / 4 + 255) / 256, 256, 0, stream>>>(Wv, Wvb, HH * HH / 4);
    cast_f32_bf16<<<(HH * HH / 4 + 255) / 256, 256, 0, stream>>>(Wo, Wob, HH * HH / 4);

    dim3 ggrid(HH / 128, M / 128);
    gemm_bt<0><<<ggrid, 256, 0, stream>>>(Xb, Wqb, nullptr, Qh, M, HH, HH);
    gemm_bt<0><<<ggrid, 256, 0, stream>>>(Xb, Wkb, nullptr, Kh, M, HH, HH);
    gemm_bt<0><<<ggrid, 256, 0, stream>>>(Xb, Wvb, nullptr, Vh, M, HH, HH);

    rope_kernel<<<(BB * NH * SS * 8) / 256, 256, 0, stream>>>(Qh, Kh, cosT, sinT);

    dim3 tgrid(SS / 64, HD / 64, BB * NH);
    transpose_v<<<tgrid, 256, 0, stream>>>(Vh, Vtg);

    attn_kernel<<<512, 256, 0, stream>>>(Qh, Kh, Vtg, Ob);

    gemm_bt<1><<<ggrid, 256, 0, stream>>>(Ob, Wob, out, nullptr, M, HH, HH);
}